// Round 7
// baseline (1660.302 us; speedup 1.0000x reference)
//
#include <hip/hip_runtime.h>
#include <hip/hip_bf16.h>
#include <stdint.h>

#define B_ 4096
#define D_ 512
#define H_ 2048
#define NS_ 16

typedef __bf16 bf16x8 __attribute__((ext_vector_type(8)));
typedef float f32x4 __attribute__((ext_vector_type(4)));
typedef short short4v __attribute__((ext_vector_type(4)));

__device__ __forceinline__ short f2bf(float f) {
  union { float f; uint32_t u; } c; c.f = f;
  uint32_t u = c.u;
  return (short)((u + 0x7fffu + ((u >> 16) & 1u)) >> 16);
}

__device__ __forceinline__ float tanh_fast(float x) {
  float e = __expf(2.0f * x);
  return 1.0f - 2.0f / (e + 1.0f);   // exp overflow -> 1, underflow -> -1 : safe
}

__device__ __forceinline__ void gload16(const void* g, void* l) {
  __builtin_amdgcn_global_load_lds((const __attribute__((address_space(1))) void*)g,
                                   (__attribute__((address_space(3))) void*)l,
                                   16, 0, 0);
}

// ===========================================================================
// Fused RNN step GEMM, v7: 1-WAVE blocks, 64x64 tile, NO LDS, NO barriers.
// 2560 blocks (~10-12 waves/CU), each wave fully self-paced; latency hidden
// by TLP across independent waves instead of intra-block scheduling.
//  - B: Wfrag packing (1KB coalesced global load per fragment, L2-resident)
//  - A: fragments loaded directly from global (16 fully-consumed 64B lines
//       per b128 frag-load; A is L2/L3-resident)
//  - Register double-buffer 1 tile ahead (X/Y sets); compiler places counted
//    vmcnt waits per-register, as late as possible.
//   [h_next | out_t] = tanh(xproj + h @ Wh) | (h @ Wout + bout)
// ===========================================================================
__global__ __launch_bounds__(64, 3) void gemm64_fused(
    const short* __restrict__ A, const short* __restrict__ Wfrag, int K,
    const float* __restrict__ xproj, const float* __restrict__ bias,
    float* __restrict__ outf, short* __restrict__ outh, int tout)
{
  const int lane = threadIdx.x;
  const int rr = lane & 15, s4 = lane >> 4;
  const int NT = K >> 5;                       // 64 K-tiles of 32

  // grid 2560 = 8 XCDs x 320; per XCD: 5 tn-cols x 64 tm-rows (tm fastest)
  // -> per-XCD B-slice = 5*64 cols * K * 2B = 1.3 MB (L2-resident)
  const int g = ((int)blockIdx.x & 7) * 320 + ((int)blockIdx.x >> 3);
  const int tm = g & 63, tn = g >> 6;
  const int row0 = tm * 64, col0 = tn * 64;

  // A fragment pointers: frag m, lane -> row0+m*16+rr, k-offset s4*8
  const short* ga0 = A + (size_t)(row0 + 0 * 16 + rr) * K + s4 * 8;
  const short* ga1 = A + (size_t)(row0 + 1 * 16 + rr) * K + s4 * 8;
  const short* ga2 = A + (size_t)(row0 + 2 * 16 + rr) * K + s4 * 8;
  const short* ga3 = A + (size_t)(row0 + 3 * 16 + rr) * K + s4 * 8;
  // B fragment base: Wfrag[(c16)*NT + kt][512], c16 = tn*4+n
  const short* gb = Wfrag + (size_t)(tn * 4) * NT * 512 + lane * 8;

  f32x4 acc[4][4];
#pragma unroll
  for (int m = 0; m < 4; ++m)
#pragma unroll
    for (int n = 0; n < 4; ++n)
      acc[m][n] = (f32x4){0.f, 0.f, 0.f, 0.f};

  bf16x8 aX[4], bX[4], aY[4], bY[4];

  // prologue: tile 0 into X
  aX[0] = *(const bf16x8*)(ga0);
  aX[1] = *(const bf16x8*)(ga1);
  aX[2] = *(const bf16x8*)(ga2);
  aX[3] = *(const bf16x8*)(ga3);
#pragma unroll
  for (int n = 0; n < 4; ++n) bX[n] = *(const bf16x8*)(gb + (size_t)n * NT * 512);

  auto iter = [&](int kt, bf16x8 (&ac)[4], bf16x8 (&bc)[4],
                  bf16x8 (&an)[4], bf16x8 (&bn)[4]) {
    const int kn = kt + 1;
    if (kn < NT) {
      const size_t ko = (size_t)kn * 32;
      an[0] = *(const bf16x8*)(ga0 + ko);
      an[1] = *(const bf16x8*)(ga1 + ko);
      an[2] = *(const bf16x8*)(ga2 + ko);
      an[3] = *(const bf16x8*)(ga3 + ko);
#pragma unroll
      for (int n = 0; n < 4; ++n)
        bn[n] = *(const bf16x8*)(gb + ((size_t)n * NT + kn) * 512);
    }
    // 16 independent MFMAs on current tile; next-tile loads in flight above
#pragma unroll
    for (int m = 0; m < 4; ++m)
#pragma unroll
      for (int n = 0; n < 4; ++n)
        acc[m][n] = __builtin_amdgcn_mfma_f32_16x16x32_bf16(ac[m], bc[n], acc[m][n], 0, 0, 0);
  };

  for (int kt = 0; kt < NT; kt += 2) {   // NT even
    iter(kt,     aX, bX, aY, bY);
    iter(kt + 1, aY, bY, aX, bX);
  }

  // ---- epilogue: C/D layout col = lane&15, row = (lane>>4)*4 + reg ----
  const int rb = row0 + s4 * 4;
  const int cb = col0 + rr;
  if (col0 < H_) {
#pragma unroll
    for (int m = 0; m < 4; ++m) {
#pragma unroll
      for (int n = 0; n < 4; ++n) {
        const int col = cb + n * 16;
#pragma unroll
        for (int r = 0; r < 4; ++r) {
          const int row = rb + m * 16 + r;
          float x = xproj[(size_t)row * H_ + col];
          outh[(size_t)row * H_ + col] = f2bf(tanh_fast(x + acc[m][n][r]));
        }
      }
    }
  } else {
#pragma unroll
    for (int m = 0; m < 4; ++m) {
#pragma unroll
      for (int n = 0; n < 4; ++n) {
        const int oc = cb - H_ + n * 16;
#pragma unroll
        for (int r = 0; r < 4; ++r) {
          const int row = rb + m * 16 + r;
          outf[(size_t)row * (NS_ * D_) + tout * D_ + oc] = acc[m][n][r] + bias[oc];
        }
      }
    }
  }
}

// Pack [Wh | Wout] columns into MFMA B-fragment order:
// Wfrag[(col>>4)*64 + (k>>5)][512] with inner (k>>3&3)*128 + (col&15)*8 + (k&7)
__global__ void wfrag_build(const float* __restrict__ Wh, const float* __restrict__ Wout,
                            short* __restrict__ Wfrag) {
  const int k = blockIdx.y;
  const int col = blockIdx.x * 256 + threadIdx.x;
  float v = (col < H_) ? Wh[(size_t)k * H_ + col]
                       : Wout[(size_t)k * D_ + (col - H_)];
  Wfrag[((size_t)(col >> 4) * 64 + (k >> 5)) * 512 +
        ((k >> 3) & 3) * 128 + (col & 15) * 8 + (k & 7)] = f2bf(v);
}

// ---------------------------------------------------------------------------
// 128-tile GEMM (round-1 structure) for xproj (EPI 0) and final out (EPI 2).
// ---------------------------------------------------------------------------
template<int BM, int BN, int EPI>
__global__ __launch_bounds__(256, 2) void gemm_bt(
    const short* __restrict__ A, const short* __restrict__ Bt, int K,
    const float* __restrict__ xproj, const float* __restrict__ bias,
    float* __restrict__ outf, short* __restrict__ outh, int ldN, int tout)
{
  constexpr int WM = BM / 2, WN = BN / 2;
  constexpr int RM = WM / 16, RN = WN / 16;
  __shared__ short lds[2][(BM + BN) * 32];
  const int tid = threadIdx.x, lane = tid & 63, wid = tid >> 6;
  const int wm = wid >> 1, wn = wid & 1;
  const int row0 = blockIdx.y * BM, col0 = blockIdx.x * BN;
  const short* Ag = A + (size_t)row0 * K;
  const short* Bg = Bt + (size_t)col0 * K;

  f32x4 acc[RM][RN];
#pragma unroll
  for (int m = 0; m < RM; ++m)
#pragma unroll
    for (int n = 0; n < RN; ++n)
      acc[m][n] = (f32x4){0.f, 0.f, 0.f, 0.f};

  const int nt = K >> 5;

  auto stage = [&](int kt, int buf) {
    const short* ga = Ag + (kt << 5);
#pragma unroll
    for (int i = 0; i < BM * 4; i += 256) {
      int slot = i + tid;
      gload16(ga + (size_t)(slot >> 2) * K + ((slot & 3) << 3), &lds[buf][slot * 8]);
    }
    const short* gb = Bg + (kt << 5);
#pragma unroll
    for (int i = 0; i < BN * 4; i += 256) {
      int slot = i + tid;
      gload16(gb + (size_t)(slot >> 2) * K + ((slot & 3) << 3),
              &lds[buf][BM * 32 + slot * 8]);
    }
  };

  stage(0, 0);
  __syncthreads();
  int cur = 0;
  const int kq = (lane >> 4) << 3;
  const int rr = lane & 15;
  for (int kt = 0; kt < nt; ++kt) {
    if (kt + 1 < nt) stage(kt + 1, cur ^ 1);
    const short* la = &lds[cur][(wm * WM) * 32];
    const short* lb = &lds[cur][BM * 32 + (wn * WN) * 32];
    bf16x8 a[RM], b[RN];
#pragma unroll
    for (int m = 0; m < RM; ++m)
      a[m] = *(const bf16x8*)(la + (m * 16 + rr) * 32 + kq);
#pragma unroll
    for (int n = 0; n < RN; ++n)
      b[n] = *(const bf16x8*)(lb + (n * 16 + rr) * 32 + kq);
#pragma unroll
    for (int m = 0; m < RM; ++m)
#pragma unroll
      for (int n = 0; n < RN; ++n)
        acc[m][n] = __builtin_amdgcn_mfma_f32_16x16x32_bf16(a[m], b[n], acc[m][n], 0, 0, 0);
    __syncthreads();
    cur ^= 1;
  }

  const int rb = row0 + wm * WM + ((lane >> 4) << 2);
  const int cb = col0 + wn * WN + (lane & 15);
#pragma unroll
  for (int m = 0; m < RM; ++m) {
#pragma unroll
    for (int n = 0; n < RN; ++n) {
      const int col = cb + n * 16;
#pragma unroll
      for (int r = 0; r < 4; ++r) {
        const int row = rb + m * 16 + r;
        float v = acc[m][n][r];
        if (EPI == 0) {
          outf[(size_t)row * ldN + col] = v + bias[col];
        } else {
          outf[(size_t)row * (NS_ * D_) + tout * D_ + col] = v + bias[col];
        }
      }
    }
  }
}

// in [R][C] fp32  ->  out [C][R] bf16
__global__ void transpose_cvt(const float* __restrict__ in, short* __restrict__ out,
                              int R, int C) {
  __shared__ float tile[32][33];
  const int tx = threadIdx.x & 31, ty = threadIdx.x >> 5;
  const int c0 = blockIdx.x * 32, r0 = blockIdx.y * 32;
#pragma unroll
  for (int i = 0; i < 32; i += 8)
    tile[ty + i][tx] = in[(size_t)(r0 + ty + i) * C + c0 + tx];
  __syncthreads();
#pragma unroll
  for (int i = 0; i < 32; i += 8)
    out[(size_t)(c0 + ty + i) * R + r0 + tx] = f2bf(tile[tx][ty + i]);
}

__global__ void cvt_bf16_k(const float4* __restrict__ in, short4v* __restrict__ out, int n4) {
  int i = blockIdx.x * 256 + threadIdx.x;
  if (i >= n4) return;
  float4 v = in[i];
  short4v o;
  o[0] = f2bf(v.x); o[1] = f2bf(v.y); o[2] = f2bf(v.z); o[3] = f2bf(v.w);
  out[i] = o;
}

__global__ void tanh_h0_k(const float4* __restrict__ xp, short4v* __restrict__ h, int n4) {
  int i = blockIdx.x * 256 + threadIdx.x;
  if (i >= n4) return;
  float4 v = xp[i];
  short4v o;
  o[0] = f2bf(tanh_fast(v.x)); o[1] = f2bf(tanh_fast(v.y));
  o[2] = f2bf(tanh_fast(v.z)); o[3] = f2bf(tanh_fast(v.w));
  h[i] = o;
}

extern "C" void kernel_launch(void* const* d_in, const int* in_sizes, int n_in,
                              void* d_out, int out_size, void* d_ws, size_t ws_size,
                              hipStream_t stream) {
  const float* z    = (const float*)d_in[0];
  const float* Wx   = (const float*)d_in[1];
  const float* Wh   = (const float*)d_in[2];
  const float* bh   = (const float*)d_in[3];
  const float* Wout = (const float*)d_in[4];
  const float* bout = (const float*)d_in[5];
  float* out = (float*)d_out;

  // workspace layout
  short* zb    = (short*)d_ws;                     // B*D bf16
  short* WxT   = zb + (size_t)B_ * D_;             // [H][D]
  short* WoutT = WxT + (size_t)H_ * D_;            // [D][H]
  short* Wfrag = WoutT + (size_t)D_ * H_;          // [2560/16][64][512]
  short* h0    = Wfrag + (size_t)(H_ + D_) * H_;   // [B][H] bf16
  short* h1    = h0 + (size_t)B_ * H_;
  float* xproj = (float*)(h1 + (size_t)B_ * H_);   // [B][H] fp32

  cvt_bf16_k<<<(B_ * D_ / 4 + 255) / 256, 256, 0, stream>>>((const float4*)z, (short4v*)zb, B_ * D_ / 4);
  transpose_cvt<<<dim3(H_ / 32, D_ / 32), 256, 0, stream>>>(Wx, WxT, D_, H_);
  transpose_cvt<<<dim3(D_ / 32, H_ / 32), 256, 0, stream>>>(Wout, WoutT, H_, D_);
  wfrag_build<<<dim3((H_ + D_) / 256, H_), 256, 0, stream>>>(Wh, Wout, Wfrag);

  // xproj = z @ Wx + bh
  gemm_bt<128, 128, 0><<<dim3(H_ / 128, B_ / 128), 256, 0, stream>>>(
      zb, WxT, D_, nullptr, bh, xproj, nullptr, H_, 0);
  // h1 = tanh(xproj)
  tanh_h0_k<<<(B_ * H_ / 4 + 255) / 256, 256, 0, stream>>>((const float4*)xproj, (short4v*)h0, B_ * H_ / 4);

  short* hb[2] = {h0, h1};
  for (int t = 1; t <= 15; ++t) {
    const short* hp = hb[(t - 1) & 1];
    short* hn = hb[t & 1];
    // fused: [h_{t+1} | out_{t-1}] = h_t @ [Wh | Wout], 2560 one-wave blocks
    gemm64_fused<<<2560, 64, 0, stream>>>(
        hp, Wfrag, H_, xproj, bout, out, hn, t - 1);
  }
  // out_15 = h16 @ Wout + bout
  gemm_bt<128, 64, 2><<<dim3(D_ / 64, B_ / 128), 256, 0, stream>>>(
      hb[1], WoutT, H_, nullptr, bout, out, nullptr, 0, 15);
}

// Round 8
// 1198.587 us; speedup vs baseline: 1.3852x; 1.3852x over previous
//
#include <hip/hip_runtime.h>
#include <hip/hip_bf16.h>
#include <stdint.h>

#define B_ 4096
#define D_ 512
#define H_ 2048
#define NS_ 16

typedef __bf16 bf16x8 __attribute__((ext_vector_type(8)));
typedef float f32x4 __attribute__((ext_vector_type(4)));
typedef short short4v __attribute__((ext_vector_type(4)));
typedef __attribute__((address_space(3))) const bf16x8* lds_frag_p;

__device__ __forceinline__ short f2bf(float f) {
  union { float f; uint32_t u; } c; c.f = f;
  uint32_t u = c.u;
  return (short)((u + 0x7fffu + ((u >> 16) & 1u)) >> 16);
}

__device__ __forceinline__ float tanh_fast(float x) {
  float e = __expf(2.0f * x);
  return 1.0f - 2.0f / (e + 1.0f);   // exp overflow -> 1, underflow -> -1 : safe
}

__device__ __forceinline__ void gload16(const void* g, void* l) {
  __builtin_amdgcn_global_load_lds((const __attribute__((address_space(1))) void*)g,
                                   (__attribute__((address_space(3))) void*)l,
                                   16, 0, 0);
}

// ===========================================================================
// Fused RNN step GEMM, v8: 128x64 tile -> 1280 blocks = 5 resident blocks/CU.
// r1's proven loop skeleton (stage-next / ds_read / MFMA / __syncthreads,
// compiler-managed waits) + r5's XOR swizzle (zero bank conflicts) + per-XCD
// contiguous tn-slices (B slice 1.3 MB, L2-resident).
//   [h_next | out_t] = tanh(xproj + h @ Wh) | (h @ Wout + bout)
// A  = h_t     [4096][2048] bf16 row-major
// Bt = Wcat^T  [2560][2048] bf16 row-major (rows = output cols)
// ===========================================================================
__global__ __launch_bounds__(256, 5) void fused_step(
    const short* __restrict__ A, const short* __restrict__ Bt, int K,
    const float* __restrict__ xproj, const float* __restrict__ bias,
    float* __restrict__ outf, short* __restrict__ outh, int tout)
{
  __shared__ short lds[2 * 6144];             // 24 KB: 2 bufs x (A 4096 + B 2048)
  const int tid = threadIdx.x, lane = tid & 63, wid = tid >> 6;
  const int wm = wid >> 1, wn = wid & 1;      // 2x2 waves; wave tile 64x32
  const int NT = K >> 5;                      // 64 K-tiles of 32

  // 1280 blocks = 8 XCDs x 160; per XCD: 5 contiguous tn-cols x 32 tm (tm fast)
  const int i = (int)blockIdx.x >> 3;
  const int tn = ((int)blockIdx.x & 7) * 5 + (i % 5);
  const int tm = i / 5;
  const int row0 = tm * 128, col0 = tn * 64;

  // ---- staging (inverse XOR swizzle on global source, rule 21) ----
  const int r0 = wid * 16 + (lane >> 2);      // 0..63
  const int r1 = r0 + 64;
  const int sl = lane & 3;
  const short* gA0 = A  + (size_t)(row0 + r0) * K + ((sl ^ ((r0 >> 1) & 3)) << 3);
  const short* gA1 = A  + (size_t)(row0 + r1) * K + ((sl ^ ((r1 >> 1) & 3)) << 3);
  const short* gB0 = Bt + (size_t)(col0 + r0) * K + ((sl ^ ((r0 >> 1) & 3)) << 3);
  const int dls = r0 * 32 + sl * 8;           // lane-linear LDS dest

  auto stage = [&](int kt, int base) {
    const size_t ko = (size_t)kt * 32;
    gload16(gA0 + ko, &lds[base + dls]);           // A rows 0..63
    gload16(gA1 + ko, &lds[base + 2048 + dls]);    // A rows 64..127
    gload16(gB0 + ko, &lds[base + 4096 + dls]);    // B rows 0..63
  };

  // ---- fragment read offsets (element units, swizzled) ----
  const int rr = lane & 15, s4 = lane >> 4;
  int offA[4], offB[2];
#pragma unroll
  for (int m = 0; m < 4; ++m) {
    int r = wm * 64 + m * 16 + rr;
    offA[m] = r * 32 + ((s4 ^ ((r >> 1) & 3)) << 3);
  }
#pragma unroll
  for (int n = 0; n < 2; ++n) {
    int r = wn * 32 + n * 16 + rr;
    offB[n] = 4096 + r * 32 + ((s4 ^ ((r >> 1) & 3)) << 3);
  }

  f32x4 acc[4][2];
#pragma unroll
  for (int m = 0; m < 4; ++m)
#pragma unroll
    for (int n = 0; n < 2; ++n)
      acc[m][n] = (f32x4){0.f, 0.f, 0.f, 0.f};

  stage(0, 0);
  __syncthreads();
  for (int kt = 0; kt < NT; ++kt) {
    if (kt + 1 < NT) stage(kt + 1, ((kt + 1) & 1) * 6144);
    const int bb = (kt & 1) * 6144;
    bf16x8 a[4], b[2];
#pragma unroll
    for (int m = 0; m < 4; ++m) a[m] = *(lds_frag_p)&lds[bb + offA[m]];
#pragma unroll
    for (int n = 0; n < 2; ++n) b[n] = *(lds_frag_p)&lds[bb + offB[n]];
#pragma unroll
    for (int m = 0; m < 4; ++m)
#pragma unroll
      for (int n = 0; n < 2; ++n)
        acc[m][n] = __builtin_amdgcn_mfma_f32_16x16x32_bf16(a[m], b[n], acc[m][n], 0, 0, 0);
    __syncthreads();
  }

  // ---- epilogue: C/D layout col = lane&15, row = (lane>>4)*4 + reg ----
  const int rb = row0 + wm * 64 + (s4 << 2);
  const int cb = col0 + wn * 32 + rr;
  if (col0 < H_) {
#pragma unroll
    for (int m = 0; m < 4; ++m) {
#pragma unroll
      for (int n = 0; n < 2; ++n) {
        const int col = cb + n * 16;
#pragma unroll
        for (int r = 0; r < 4; ++r) {
          const int row = rb + m * 16 + r;
          float x = xproj[(size_t)row * H_ + col];
          outh[(size_t)row * H_ + col] = f2bf(tanh_fast(x + acc[m][n][r]));
        }
      }
    }
  } else {
#pragma unroll
    for (int m = 0; m < 4; ++m) {
#pragma unroll
      for (int n = 0; n < 2; ++n) {
        const int oc = cb - H_ + n * 16;
#pragma unroll
        for (int r = 0; r < 4; ++r) {
          const int row = rb + m * 16 + r;
          outf[(size_t)row * (NS_ * D_) + tout * D_ + oc] = acc[m][n][r] + bias[oc];
        }
      }
    }
  }
}

// ---------------------------------------------------------------------------
// 128-tile GEMM (round-1 structure) for xproj (EPI 0) and final out (EPI 2).
// ---------------------------------------------------------------------------
template<int BM, int BN, int EPI>
__global__ __launch_bounds__(256, 2) void gemm_bt(
    const short* __restrict__ A, const short* __restrict__ Bt, int K,
    const float* __restrict__ xproj, const float* __restrict__ bias,
    float* __restrict__ outf, short* __restrict__ outh, int ldN, int tout)
{
  constexpr int WM = BM / 2, WN = BN / 2;
  constexpr int RM = WM / 16, RN = WN / 16;
  __shared__ short lds[2][(BM + BN) * 32];
  const int tid = threadIdx.x, lane = tid & 63, wid = tid >> 6;
  const int wm = wid >> 1, wn = wid & 1;
  const int row0 = blockIdx.y * BM, col0 = blockIdx.x * BN;
  const short* Ag = A + (size_t)row0 * K;
  const short* Bg = Bt + (size_t)col0 * K;

  f32x4 acc[RM][RN];
#pragma unroll
  for (int m = 0; m < RM; ++m)
#pragma unroll
    for (int n = 0; n < RN; ++n)
      acc[m][n] = (f32x4){0.f, 0.f, 0.f, 0.f};

  const int nt = K >> 5;

  auto stage = [&](int kt, int buf) {
    const short* ga = Ag + (kt << 5);
#pragma unroll
    for (int i = 0; i < BM * 4; i += 256) {
      int slot = i + tid;
      gload16(ga + (size_t)(slot >> 2) * K + ((slot & 3) << 3), &lds[buf][slot * 8]);
    }
    const short* gb = Bg + (kt << 5);
#pragma unroll
    for (int i = 0; i < BN * 4; i += 256) {
      int slot = i + tid;
      gload16(gb + (size_t)(slot >> 2) * K + ((slot & 3) << 3),
              &lds[buf][BM * 32 + slot * 8]);
    }
  };

  stage(0, 0);
  __syncthreads();
  int cur = 0;
  const int kq = (lane >> 4) << 3;
  const int rr = lane & 15;
  for (int kt = 0; kt < nt; ++kt) {
    if (kt + 1 < nt) stage(kt + 1, cur ^ 1);
    const short* la = &lds[cur][(wm * WM) * 32];
    const short* lb = &lds[cur][BM * 32 + (wn * WN) * 32];
    bf16x8 a[RM], b[RN];
#pragma unroll
    for (int m = 0; m < RM; ++m)
      a[m] = *(const bf16x8*)(la + (m * 16 + rr) * 32 + kq);
#pragma unroll
    for (int n = 0; n < RN; ++n)
      b[n] = *(const bf16x8*)(lb + (n * 16 + rr) * 32 + kq);
#pragma unroll
    for (int m = 0; m < RM; ++m)
#pragma unroll
      for (int n = 0; n < RN; ++n)
        acc[m][n] = __builtin_amdgcn_mfma_f32_16x16x32_bf16(a[m], b[n], acc[m][n], 0, 0, 0);
    __syncthreads();
    cur ^= 1;
  }

  const int rb = row0 + wm * WM + ((lane >> 4) << 2);
  const int cb = col0 + wn * WN + (lane & 15);
#pragma unroll
  for (int m = 0; m < RM; ++m) {
#pragma unroll
    for (int n = 0; n < RN; ++n) {
      const int col = cb + n * 16;
#pragma unroll
      for (int r = 0; r < 4; ++r) {
        const int row = rb + m * 16 + r;
        float v = acc[m][n][r];
        if (EPI == 0) {
          outf[(size_t)row * ldN + col] = v + bias[col];
        } else {
          outf[(size_t)row * (NS_ * D_) + tout * D_ + col] = v + bias[col];
        }
      }
    }
  }
}

// in [R][C] fp32  ->  out [C][R] bf16
__global__ void transpose_cvt(const float* __restrict__ in, short* __restrict__ out,
                              int R, int C) {
  __shared__ float tile[32][33];
  const int tx = threadIdx.x & 31, ty = threadIdx.x >> 5;
  const int c0 = blockIdx.x * 32, r0 = blockIdx.y * 32;
#pragma unroll
  for (int i = 0; i < 32; i += 8)
    tile[ty + i][tx] = in[(size_t)(r0 + ty + i) * C + c0 + tx];
  __syncthreads();
#pragma unroll
  for (int i = 0; i < 32; i += 8)
    out[(size_t)(c0 + ty + i) * R + r0 + tx] = f2bf(tile[tx][ty + i]);
}

__global__ void cvt_bf16_k(const float4* __restrict__ in, short4v* __restrict__ out, int n4) {
  int i = blockIdx.x * 256 + threadIdx.x;
  if (i >= n4) return;
  float4 v = in[i];
  short4v o;
  o[0] = f2bf(v.x); o[1] = f2bf(v.y); o[2] = f2bf(v.z); o[3] = f2bf(v.w);
  out[i] = o;
}

__global__ void tanh_h0_k(const float4* __restrict__ xp, short4v* __restrict__ h, int n4) {
  int i = blockIdx.x * 256 + threadIdx.x;
  if (i >= n4) return;
  float4 v = xp[i];
  short4v o;
  o[0] = f2bf(tanh_fast(v.x)); o[1] = f2bf(tanh_fast(v.y));
  o[2] = f2bf(tanh_fast(v.z)); o[3] = f2bf(tanh_fast(v.w));
  h[i] = o;
}

extern "C" void kernel_launch(void* const* d_in, const int* in_sizes, int n_in,
                              void* d_out, int out_size, void* d_ws, size_t ws_size,
                              hipStream_t stream) {
  const float* z    = (const float*)d_in[0];
  const float* Wx   = (const float*)d_in[1];
  const float* Wh   = (const float*)d_in[2];
  const float* bh   = (const float*)d_in[3];
  const float* Wout = (const float*)d_in[4];
  const float* bout = (const float*)d_in[5];
  float* out = (float*)d_out;

  // workspace layout
  short* zb    = (short*)d_ws;                     // B*D bf16
  short* WxT   = zb + (size_t)B_ * D_;             // [H][D]
  short* WcatT = WxT + (size_t)H_ * D_;            // [H+D][H]  (WhT then WoutT)
  short* WoutT = WcatT + (size_t)H_ * H_;
  short* h0    = WcatT + (size_t)(H_ + D_) * H_;   // [B][H] bf16
  short* h1    = h0 + (size_t)B_ * H_;
  float* xproj = (float*)(h1 + (size_t)B_ * H_);   // [B][H] fp32

  cvt_bf16_k<<<(B_ * D_ / 4 + 255) / 256, 256, 0, stream>>>((const float4*)z, (short4v*)zb, B_ * D_ / 4);
  transpose_cvt<<<dim3(H_ / 32, D_ / 32), 256, 0, stream>>>(Wx, WxT, D_, H_);
  transpose_cvt<<<dim3(H_ / 32, H_ / 32), 256, 0, stream>>>(Wh, WcatT, H_, H_);
  transpose_cvt<<<dim3(D_ / 32, H_ / 32), 256, 0, stream>>>(Wout, WoutT, H_, D_);

  // xproj = z @ Wx + bh
  gemm_bt<128, 128, 0><<<dim3(H_ / 128, B_ / 128), 256, 0, stream>>>(
      zb, WxT, D_, nullptr, bh, xproj, nullptr, H_, 0);
  // h1 = tanh(xproj)
  tanh_h0_k<<<(B_ * H_ / 4 + 255) / 256, 256, 0, stream>>>((const float4*)xproj, (short4v*)h0, B_ * H_ / 4);

  short* hb[2] = {h0, h1};
  for (int t = 1; t <= 15; ++t) {
    const short* hp = hb[(t - 1) & 1];
    short* hn = hb[t & 1];
    // fused: [h_{t+1} | out_{t-1}] = h_t @ [Wh | Wout], 1280 blocks (5/CU)
    fused_step<<<1280, 256, 0, stream>>>(
        hp, WcatT, H_, xproj, bout, out, hn, t - 1);
  }
  // out_15 = h16 @ Wout + bout
  gemm_bt<128, 64, 2><<<dim3(D_ / 64, B_ / 128), 256, 0, stream>>>(
      hb[1], WoutT, H_, nullptr, bout, out, nullptr, 0, 15);
}